// Round 2
// baseline (71.494 us; speedup 1.0000x reference)
//
#include <hip/hip_runtime.h>
#include <hip/hip_bf16.h>

// SurfaceLoss: B=4, P=100000, K=32
//   n_unit  = n / max(||n||, 1e-17)
//   w_k     = exp(-||kn_unit_k - n_unit||^2 / 0.5625)
//   out     = sum(kn_k * w_k) / max(sum(w_k), 1e-17)
//
// VMEM-issue-bound op: minimize VMEM instruction count.
//  - one dwordx4 per neighbor gather (shift trick at idx==P-1 stays in-bounds)
//  - 2 threads per point (16 neighbors each), pair-reduce via shfl_xor(1)

#define SL_B 4
#define SL_P 100000
#define SL_K 32
#define SL_HALF 16
#define SL_INV_SIG2 1.77777779f   // 1/(0.75*0.75)
#define SL_EPS 1e-17f

__global__ __launch_bounds__(256) void SurfaceLoss_kernel(
    const float* __restrict__ normals,   // [B,P,3]
    const int*   __restrict__ knn,       // [B,P,K] (int32)
    float*       __restrict__ out)       // [B,P,3]
{
    int gid = blockIdx.x * blockDim.x + threadIdx.x;
    int p = gid >> 1;                    // global point id in [0, B*P)
    if (p >= SL_B * SL_P) return;
    int h = gid & 1;                     // which half of K this thread owns
    int b = p / SL_P;
    int pl = p - b * SL_P;               // local point index within batch

    const float* nb = normals + (size_t)b * (SL_P * 3);

    // ---- center normal: one dwordx4 (shifted at the last point to stay in-bounds)
    {
        // handled below together with unit computation
    }
    int coff = pl * 3;
    bool clast = (pl == SL_P - 1);
    float4 cv = *reinterpret_cast<const float4*>(nb + (clast ? coff - 1 : coff));
    float nx = clast ? cv.y : cv.x;
    float ny = clast ? cv.z : cv.y;
    float nz = clast ? cv.w : cv.z;
    float ninv = 1.0f / fmaxf(sqrtf(nx * nx + ny * ny + nz * nz), SL_EPS);
    float ux = nx * ninv, uy = ny * ninv, uz = nz * ninv;

    // ---- load this thread's 16 neighbor indices (4x int4, fully coalesced)
    int kid[SL_HALF];
    const int4* kp = reinterpret_cast<const int4*>(knn + (size_t)p * SL_K + h * SL_HALF);
#pragma unroll
    for (int j = 0; j < 4; ++j) {
        int4 q = kp[j];
        kid[4 * j + 0] = q.x;
        kid[4 * j + 1] = q.y;
        kid[4 * j + 2] = q.z;
        kid[4 * j + 3] = q.w;
    }

    float numx = 0.f, numy = 0.f, numz = 0.f, den = 0.f;

#pragma unroll
    for (int k = 0; k < SL_HALF; ++k) {
        int idx = kid[k];
        int off = idx * 3;
        bool last = (idx == SL_P - 1);
        float4 v = *reinterpret_cast<const float4*>(nb + (last ? off - 1 : off));
        float kx = last ? v.y : v.x;
        float ky = last ? v.z : v.y;
        float kz = last ? v.w : v.z;
        float kinv = 1.0f / fmaxf(sqrtf(kx * kx + ky * ky + kz * kz), SL_EPS);
        float dx = fmaf(kx, kinv, -ux);
        float dy = fmaf(ky, kinv, -uy);
        float dz = fmaf(kz, kinv, -uz);
        float d2 = dx * dx + dy * dy + dz * dz;
        float w = __expf(-d2 * SL_INV_SIG2);
        numx = fmaf(kx, w, numx);
        numy = fmaf(ky, w, numy);
        numz = fmaf(kz, w, numz);
        den += w;
    }

    // ---- pair reduction (lanes 2i and 2i+1 hold halves of the same point)
    numx += __shfl_xor(numx, 1);
    numy += __shfl_xor(numy, 1);
    numz += __shfl_xor(numz, 1);
    den  += __shfl_xor(den, 1);

    if (h == 0) {
        float dinv = 1.0f / fmaxf(den, SL_EPS);
        out[3 * (size_t)p + 0] = numx * dinv;
        out[3 * (size_t)p + 1] = numy * dinv;
        out[3 * (size_t)p + 2] = numz * dinv;
    }
}

extern "C" void kernel_launch(void* const* d_in, const int* in_sizes, int n_in,
                              void* d_out, int out_size, void* d_ws, size_t ws_size,
                              hipStream_t stream) {
    const float* normals = (const float*)d_in[0];
    const int*   knn     = (const int*)d_in[1];
    float*       out     = (float*)d_out;

    int total = SL_B * SL_P * 2;             // 800000 threads (2 per point)
    int block = 256;
    int grid = (total + block - 1) / block;  // 3125 blocks
    SurfaceLoss_kernel<<<grid, block, 0, stream>>>(normals, knn, out);
}

// Round 3
// 66.793 us; speedup vs baseline: 1.0704x; 1.0704x over previous
//
#include <hip/hip_runtime.h>
#include <hip/hip_fp16.h>

// SurfaceLoss: B=4, P=100000, K=32
//   n_unit  = n / max(||n||, 1e-17)
//   w_k     = exp(-||kn_unit_k - n_unit||^2 / 0.5625)
//   out     = sum(kn_k * w_k) / max(sum(w_k), 1e-17)
//
// Bottleneck model (R1/R2 evidence): divergent gathers cost 1 TCP cycle per
// lane-transaction. Unaligned 12B-stride float4 gathers split into 4
// transactions. Fix: pass 1 packs {unit,len} into ALIGNED 8-byte f16 records
// (also L2-resident: 3.2 MB < 4 MiB/XCD); pass 2 gathers 1 dwordx2 each.

#define SL_B 4
#define SL_P 100000
#define SL_K 32
#define SL_HALF 16
#define SL_EPS 1e-17f
#define SL_2INV 3.55555558f   // 2/(0.75*0.75)

union SlPk { float2 f; __half2 h[2]; };

// ---- pass 1: normals [B*P,3] -> rec[p] = {ux,uy,uz,len} packed 4xf16 (8B)
__global__ __launch_bounds__(256) void sl_pack(
    const float* __restrict__ normals,
    float2* __restrict__ rec)
{
    int p = blockIdx.x * blockDim.x + threadIdx.x;
    if (p >= SL_B * SL_P) return;
    float nx = normals[3 * (size_t)p + 0];
    float ny = normals[3 * (size_t)p + 1];
    float nz = normals[3 * (size_t)p + 2];
    float len = sqrtf(nx * nx + ny * ny + nz * nz);
    float inv = 1.0f / fmaxf(len, SL_EPS);
    SlPk pk;
    pk.h[0] = __floats2half2_rn(nx * inv, ny * inv);
    pk.h[1] = __floats2half2_rn(nz * inv, len);
    rec[p] = pk.f;
}

// ---- pass 2: 2 threads per point, 16 aligned 8B gathers each
__global__ __launch_bounds__(256) void sl_main(
    const float2* __restrict__ rec,      // [B*P] packed records
    const int*    __restrict__ knn,      // [B,P,K] (int32)
    float*        __restrict__ out)      // [B,P,3]
{
    int gid = blockIdx.x * blockDim.x + threadIdx.x;
    int p = gid >> 1;
    if (p >= SL_B * SL_P) return;
    int h = gid & 1;
    int b = p / SL_P;
    const float2* rb = rec + (size_t)b * SL_P;   // batch-local records
    int pl = p - b * SL_P;

    // own unit normal
    SlPk cp; cp.f = rb[pl];
    float ux = __low2float(cp.h[0]);
    float uy = __high2float(cp.h[0]);
    float uz = __low2float(cp.h[1]);

    // 16 neighbor indices (4x int4, coalesced)
    int kid[SL_HALF];
    const int4* kp = reinterpret_cast<const int4*>(knn + (size_t)p * SL_K + h * SL_HALF);
#pragma unroll
    for (int j = 0; j < 4; ++j) {
        int4 q = kp[j];
        kid[4 * j + 0] = q.x;
        kid[4 * j + 1] = q.y;
        kid[4 * j + 2] = q.z;
        kid[4 * j + 3] = q.w;
    }

    float numx = 0.f, numy = 0.f, numz = 0.f, den = 0.f;

#pragma unroll
    for (int k = 0; k < SL_HALF; ++k) {
        SlPk pk; pk.f = rb[kid[k]];              // one aligned 8B transaction
        float kx = __low2float(pk.h[0]);
        float ky = __high2float(pk.h[0]);
        float kz = __low2float(pk.h[1]);
        float kl = __high2float(pk.h[1]);
        // ||ku-u||^2 = 2 - 2*dot  (both unit)
        float d = kx * ux;
        d = fmaf(ky, uy, d);
        d = fmaf(kz, uz, d);
        float w = __expf(fmaf(d, SL_2INV, -SL_2INV));
        float s = w * kl;                        // weight * len -> raw normal scale
        numx = fmaf(kx, s, numx);
        numy = fmaf(ky, s, numy);
        numz = fmaf(kz, s, numz);
        den += w;
    }

    numx += __shfl_xor(numx, 1);
    numy += __shfl_xor(numy, 1);
    numz += __shfl_xor(numz, 1);
    den  += __shfl_xor(den, 1);

    if (h == 0) {
        float dinv = 1.0f / fmaxf(den, SL_EPS);
        out[3 * (size_t)p + 0] = numx * dinv;
        out[3 * (size_t)p + 1] = numy * dinv;
        out[3 * (size_t)p + 2] = numz * dinv;
    }
}

// ---- fallback (ws too small): round-2 single-pass kernel
__global__ __launch_bounds__(256) void sl_fallback(
    const float* __restrict__ normals,
    const int*   __restrict__ knn,
    float*       __restrict__ out)
{
    int gid = blockIdx.x * blockDim.x + threadIdx.x;
    int p = gid >> 1;
    if (p >= SL_B * SL_P) return;
    int h = gid & 1;
    int b = p / SL_P;
    int pl = p - b * SL_P;
    const float* nb = normals + (size_t)b * (SL_P * 3);

    int coff = pl * 3;
    bool clast = (pl == SL_P - 1);
    float4 cv = *reinterpret_cast<const float4*>(nb + (clast ? coff - 1 : coff));
    float nx = clast ? cv.y : cv.x;
    float ny = clast ? cv.z : cv.y;
    float nz = clast ? cv.w : cv.z;
    float ninv = 1.0f / fmaxf(sqrtf(nx * nx + ny * ny + nz * nz), SL_EPS);
    float ux = nx * ninv, uy = ny * ninv, uz = nz * ninv;

    int kid[SL_HALF];
    const int4* kp = reinterpret_cast<const int4*>(knn + (size_t)p * SL_K + h * SL_HALF);
#pragma unroll
    for (int j = 0; j < 4; ++j) {
        int4 q = kp[j];
        kid[4 * j + 0] = q.x; kid[4 * j + 1] = q.y;
        kid[4 * j + 2] = q.z; kid[4 * j + 3] = q.w;
    }
    float numx = 0.f, numy = 0.f, numz = 0.f, den = 0.f;
#pragma unroll
    for (int k = 0; k < SL_HALF; ++k) {
        int idx = kid[k];
        int off = idx * 3;
        bool last = (idx == SL_P - 1);
        float4 v = *reinterpret_cast<const float4*>(nb + (last ? off - 1 : off));
        float kx = last ? v.y : v.x;
        float ky = last ? v.z : v.y;
        float kz = last ? v.w : v.z;
        float kinv = 1.0f / fmaxf(sqrtf(kx * kx + ky * ky + kz * kz), SL_EPS);
        float dx = fmaf(kx, kinv, -ux);
        float dy = fmaf(ky, kinv, -uy);
        float dz = fmaf(kz, kinv, -uz);
        float d2 = dx * dx + dy * dy + dz * dz;
        float w = __expf(-d2 * 1.77777779f);
        numx = fmaf(kx, w, numx);
        numy = fmaf(ky, w, numy);
        numz = fmaf(kz, w, numz);
        den += w;
    }
    numx += __shfl_xor(numx, 1);
    numy += __shfl_xor(numy, 1);
    numz += __shfl_xor(numz, 1);
    den  += __shfl_xor(den, 1);
    if (h == 0) {
        float dinv = 1.0f / fmaxf(den, SL_EPS);
        out[3 * (size_t)p + 0] = numx * dinv;
        out[3 * (size_t)p + 1] = numy * dinv;
        out[3 * (size_t)p + 2] = numz * dinv;
    }
}

extern "C" void kernel_launch(void* const* d_in, const int* in_sizes, int n_in,
                              void* d_out, int out_size, void* d_ws, size_t ws_size,
                              hipStream_t stream) {
    const float* normals = (const float*)d_in[0];
    const int*   knn     = (const int*)d_in[1];
    float*       out     = (float*)d_out;

    const size_t need = (size_t)SL_B * SL_P * sizeof(float2);  // 3.2 MB
    if (ws_size >= need) {
        float2* rec = (float2*)d_ws;
        int n1 = SL_B * SL_P;
        sl_pack<<<(n1 + 255) / 256, 256, 0, stream>>>(normals, rec);
        int n2 = SL_B * SL_P * 2;
        sl_main<<<(n2 + 255) / 256, 256, 0, stream>>>(rec, knn, out);
    } else {
        int n2 = SL_B * SL_P * 2;
        sl_fallback<<<(n2 + 255) / 256, 256, 0, stream>>>(normals, knn, out);
    }
}

// Round 4
// 66.420 us; speedup vs baseline: 1.0764x; 1.0056x over previous
//
#include <hip/hip_runtime.h>
#include <hip/hip_fp16.h>

// SurfaceLoss: B=4, P=100000, K=32
//   n_unit  = n / max(||n||, 1e-17)
//   w_k     = exp(-||kn_unit_k - n_unit||^2 / 0.5625)
//   out     = sum(kn_k * w_k) / max(sum(w_k), 1e-17)
//
// R3 evidence: latency-bound, MLP-starved (VGPR=32 forced serial gathers).
// R4 change: two-phase per thread — issue ALL 16 record gathers into regs,
// then compute. launch_bounds(256,6) gives VGPR headroom (<=85) at 24 waves/CU.

#define SL_B 4
#define SL_P 100000
#define SL_K 32
#define SL_HALF 16
#define SL_EPS 1e-17f
#define SL_2INV 3.55555558f   // 2/(0.75*0.75)

union SlPk { float2 f; __half2 h[2]; };

// ---- pass 1: normals [B*P,3] -> rec[p] = {ux,uy,uz,len} packed 4xf16 (8B)
__global__ __launch_bounds__(256) void sl_pack(
    const float* __restrict__ normals,
    float2* __restrict__ rec)
{
    int p = blockIdx.x * blockDim.x + threadIdx.x;
    if (p >= SL_B * SL_P) return;
    float nx = normals[3 * (size_t)p + 0];
    float ny = normals[3 * (size_t)p + 1];
    float nz = normals[3 * (size_t)p + 2];
    float len = sqrtf(nx * nx + ny * ny + nz * nz);
    float inv = 1.0f / fmaxf(len, SL_EPS);
    SlPk pk;
    pk.h[0] = __floats2half2_rn(nx * inv, ny * inv);
    pk.h[1] = __floats2half2_rn(nz * inv, len);
    rec[p] = pk.f;
}

// ---- pass 2: 2 threads per point; ALL 16 gathers in flight, then compute
__global__ __launch_bounds__(256, 6) void sl_main(
    const float2* __restrict__ rec,      // [B*P] packed records
    const int*    __restrict__ knn,      // [B,P,K] (int32)
    float*        __restrict__ out)      // [B,P,3]
{
    int gid = blockIdx.x * blockDim.x + threadIdx.x;
    int p = gid >> 1;
    if (p >= SL_B * SL_P) return;
    int h = gid & 1;
    int b = p / SL_P;
    const float2* rb = rec + (size_t)b * SL_P;
    int pl = p - b * SL_P;

    // 16 neighbor indices (4x int4, coalesced)
    int kid[SL_HALF];
    const int4* kp = reinterpret_cast<const int4*>(knn + (size_t)p * SL_K + h * SL_HALF);
#pragma unroll
    for (int j = 0; j < 4; ++j) {
        int4 q = kp[j];
        kid[4 * j + 0] = q.x;
        kid[4 * j + 1] = q.y;
        kid[4 * j + 2] = q.z;
        kid[4 * j + 3] = q.w;
    }

    // phase 1: issue ALL record gathers (stay in regs; no compute between)
    float2 rv[SL_HALF];
#pragma unroll
    for (int k = 0; k < SL_HALF; ++k) rv[k] = rb[kid[k]];
    SlPk cp; cp.f = rb[pl];              // own record (issued after; small)

    float ux = __low2float(cp.h[0]);
    float uy = __high2float(cp.h[0]);
    float uz = __low2float(cp.h[1]);

    // phase 2: compute (consumes rv[k] in issue order — loads drain in flight)
    float numx = 0.f, numy = 0.f, numz = 0.f, den = 0.f;
#pragma unroll
    for (int k = 0; k < SL_HALF; ++k) {
        SlPk pk; pk.f = rv[k];
        float kx = __low2float(pk.h[0]);
        float ky = __high2float(pk.h[0]);
        float kz = __low2float(pk.h[1]);
        float kl = __high2float(pk.h[1]);
        // ||ku-u||^2 = 2 - 2*dot  (both unit)
        float d = kx * ux;
        d = fmaf(ky, uy, d);
        d = fmaf(kz, uz, d);
        float w = __expf(fmaf(d, SL_2INV, -SL_2INV));
        float s = w * kl;
        numx = fmaf(kx, s, numx);
        numy = fmaf(ky, s, numy);
        numz = fmaf(kz, s, numz);
        den += w;
    }

    numx += __shfl_xor(numx, 1);
    numy += __shfl_xor(numy, 1);
    numz += __shfl_xor(numz, 1);
    den  += __shfl_xor(den, 1);

    if (h == 0) {
        float dinv = 1.0f / fmaxf(den, SL_EPS);
        out[3 * (size_t)p + 0] = numx * dinv;
        out[3 * (size_t)p + 1] = numy * dinv;
        out[3 * (size_t)p + 2] = numz * dinv;
    }
}

// ---- fallback (ws too small): single-pass kernel
__global__ __launch_bounds__(256) void sl_fallback(
    const float* __restrict__ normals,
    const int*   __restrict__ knn,
    float*       __restrict__ out)
{
    int gid = blockIdx.x * blockDim.x + threadIdx.x;
    int p = gid >> 1;
    if (p >= SL_B * SL_P) return;
    int h = gid & 1;
    int b = p / SL_P;
    int pl = p - b * SL_P;
    const float* nb = normals + (size_t)b * (SL_P * 3);

    int coff = pl * 3;
    bool clast = (pl == SL_P - 1);
    float4 cv = *reinterpret_cast<const float4*>(nb + (clast ? coff - 1 : coff));
    float nx = clast ? cv.y : cv.x;
    float ny = clast ? cv.z : cv.y;
    float nz = clast ? cv.w : cv.z;
    float ninv = 1.0f / fmaxf(sqrtf(nx * nx + ny * ny + nz * nz), SL_EPS);
    float ux = nx * ninv, uy = ny * ninv, uz = nz * ninv;

    int kid[SL_HALF];
    const int4* kp = reinterpret_cast<const int4*>(knn + (size_t)p * SL_K + h * SL_HALF);
#pragma unroll
    for (int j = 0; j < 4; ++j) {
        int4 q = kp[j];
        kid[4 * j + 0] = q.x; kid[4 * j + 1] = q.y;
        kid[4 * j + 2] = q.z; kid[4 * j + 3] = q.w;
    }
    float numx = 0.f, numy = 0.f, numz = 0.f, den = 0.f;
#pragma unroll
    for (int k = 0; k < SL_HALF; ++k) {
        int idx = kid[k];
        int off = idx * 3;
        bool last = (idx == SL_P - 1);
        float4 v = *reinterpret_cast<const float4*>(nb + (last ? off - 1 : off));
        float kx = last ? v.y : v.x;
        float ky = last ? v.z : v.y;
        float kz = last ? v.w : v.z;
        float kinv = 1.0f / fmaxf(sqrtf(kx * kx + ky * ky + kz * kz), SL_EPS);
        float dx = fmaf(kx, kinv, -ux);
        float dy = fmaf(ky, kinv, -uy);
        float dz = fmaf(kz, kinv, -uz);
        float d2 = dx * dx + dy * dy + dz * dz;
        float w = __expf(-d2 * 1.77777779f);
        numx = fmaf(kx, w, numx);
        numy = fmaf(ky, w, numy);
        numz = fmaf(kz, w, numz);
        den += w;
    }
    numx += __shfl_xor(numx, 1);
    numy += __shfl_xor(numy, 1);
    numz += __shfl_xor(numz, 1);
    den  += __shfl_xor(den, 1);
    if (h == 0) {
        float dinv = 1.0f / fmaxf(den, SL_EPS);
        out[3 * (size_t)p + 0] = numx * dinv;
        out[3 * (size_t)p + 1] = numy * dinv;
        out[3 * (size_t)p + 2] = numz * dinv;
    }
}

extern "C" void kernel_launch(void* const* d_in, const int* in_sizes, int n_in,
                              void* d_out, int out_size, void* d_ws, size_t ws_size,
                              hipStream_t stream) {
    const float* normals = (const float*)d_in[0];
    const int*   knn     = (const int*)d_in[1];
    float*       out     = (float*)d_out;

    const size_t need = (size_t)SL_B * SL_P * sizeof(float2);  // 3.2 MB
    if (ws_size >= need) {
        float2* rec = (float2*)d_ws;
        int n1 = SL_B * SL_P;
        sl_pack<<<(n1 + 255) / 256, 256, 0, stream>>>(normals, rec);
        int n2 = SL_B * SL_P * 2;
        sl_main<<<(n2 + 255) / 256, 256, 0, stream>>>(rec, knn, out);
    } else {
        int n2 = SL_B * SL_P * 2;
        sl_fallback<<<(n2 + 255) / 256, 256, 0, stream>>>(normals, knn, out);
    }
}

// Round 5
// 66.115 us; speedup vs baseline: 1.0814x; 1.0046x over previous
//
#include <hip/hip_runtime.h>
#include <hip/hip_fp16.h>

// SurfaceLoss: B=4, P=100000, K=32
//   n_unit  = n / max(||n||, 1e-17)
//   w_k     = exp(-||kn_unit_k - n_unit||^2 / 0.5625)
//   out     = sum(kn_k * w_k) / max(sum(w_k), 1e-17)
//
// R4 evidence: compiler re-pipelined the load/compute phases (VGPR stayed 32),
// keeping only ~4 gathers in flight -> latency-bound at ~62us.
// R5: sched_barrier(0) between gather phase and compute phase forces all 16
// float2 results live -> ~300 outstanding gathers/CU, latency hidden.

#define SL_B 4
#define SL_P 100000
#define SL_K 32
#define SL_HALF 16
#define SL_EPS 1e-17f
#define SL_2INV 3.55555558f   // 2/(0.75*0.75)

union SlPk { float2 f; __half2 h[2]; };

// ---- pass 1: normals [B*P,3] -> rec[p] = {ux,uy,uz,len} packed 4xf16 (8B)
__global__ __launch_bounds__(256) void sl_pack(
    const float* __restrict__ normals,
    float2* __restrict__ rec)
{
    int p = blockIdx.x * blockDim.x + threadIdx.x;
    if (p >= SL_B * SL_P) return;
    float nx = normals[3 * (size_t)p + 0];
    float ny = normals[3 * (size_t)p + 1];
    float nz = normals[3 * (size_t)p + 2];
    float len = sqrtf(nx * nx + ny * ny + nz * nz);
    float inv = 1.0f / fmaxf(len, SL_EPS);
    SlPk pk;
    pk.h[0] = __floats2half2_rn(nx * inv, ny * inv);
    pk.h[1] = __floats2half2_rn(nz * inv, len);
    rec[p] = pk.f;
}

// ---- pass 2: 2 threads per point; ALL 16 gathers forced in flight
__global__ __launch_bounds__(256) void sl_main(
    const float2* __restrict__ rec,      // [B*P] packed records
    const int*    __restrict__ knn,      // [B,P,K] (int32)
    float*        __restrict__ out)      // [B,P,3]
{
    int gid = blockIdx.x * blockDim.x + threadIdx.x;
    int p = gid >> 1;
    if (p >= SL_B * SL_P) return;
    int h = gid & 1;
    int b = p / SL_P;
    const float2* rb = rec + (size_t)b * SL_P;
    int pl = p - b * SL_P;

    // 16 neighbor indices (4x int4, coalesced)
    int kid[SL_HALF];
    const int4* kp = reinterpret_cast<const int4*>(knn + (size_t)p * SL_K + h * SL_HALF);
#pragma unroll
    for (int j = 0; j < 4; ++j) {
        int4 q = kp[j];
        kid[4 * j + 0] = q.x;
        kid[4 * j + 1] = q.y;
        kid[4 * j + 2] = q.z;
        kid[4 * j + 3] = q.w;
    }

    // phase 1: own record + ALL 16 gathers issued; results forced live
    SlPk cp; cp.f = rb[pl];
    float2 rv[SL_HALF];
#pragma unroll
    for (int k = 0; k < SL_HALF; ++k) rv[k] = rb[kid[k]];

    // hard scheduling fence: nothing moves across — all loads must be issued
    // (and their dest regs allocated) before any compute below is scheduled.
    __builtin_amdgcn_sched_barrier(0);

    float ux = __low2float(cp.h[0]);
    float uy = __high2float(cp.h[0]);
    float uz = __low2float(cp.h[1]);

    // phase 2: consume in issue order (vmcnt drains progressively)
    float numx = 0.f, numy = 0.f, numz = 0.f, den = 0.f;
#pragma unroll
    for (int k = 0; k < SL_HALF; ++k) {
        SlPk pk; pk.f = rv[k];
        float kx = __low2float(pk.h[0]);
        float ky = __high2float(pk.h[0]);
        float kz = __low2float(pk.h[1]);
        float kl = __high2float(pk.h[1]);
        // ||ku-u||^2 = 2 - 2*dot  (both unit)
        float d = kx * ux;
        d = fmaf(ky, uy, d);
        d = fmaf(kz, uz, d);
        float w = __expf(fmaf(d, SL_2INV, -SL_2INV));
        float s = w * kl;
        numx = fmaf(kx, s, numx);
        numy = fmaf(ky, s, numy);
        numz = fmaf(kz, s, numz);
        den += w;
    }

    numx += __shfl_xor(numx, 1);
    numy += __shfl_xor(numy, 1);
    numz += __shfl_xor(numz, 1);
    den  += __shfl_xor(den, 1);

    if (h == 0) {
        float dinv = 1.0f / fmaxf(den, SL_EPS);
        out[3 * (size_t)p + 0] = numx * dinv;
        out[3 * (size_t)p + 1] = numy * dinv;
        out[3 * (size_t)p + 2] = numz * dinv;
    }
}

// ---- fallback (ws too small): single-pass kernel
__global__ __launch_bounds__(256) void sl_fallback(
    const float* __restrict__ normals,
    const int*   __restrict__ knn,
    float*       __restrict__ out)
{
    int gid = blockIdx.x * blockDim.x + threadIdx.x;
    int p = gid >> 1;
    if (p >= SL_B * SL_P) return;
    int h = gid & 1;
    int b = p / SL_P;
    int pl = p - b * SL_P;
    const float* nb = normals + (size_t)b * (SL_P * 3);

    int coff = pl * 3;
    bool clast = (pl == SL_P - 1);
    float4 cv = *reinterpret_cast<const float4*>(nb + (clast ? coff - 1 : coff));
    float nx = clast ? cv.y : cv.x;
    float ny = clast ? cv.z : cv.y;
    float nz = clast ? cv.w : cv.z;
    float ninv = 1.0f / fmaxf(sqrtf(nx * nx + ny * ny + nz * nz), SL_EPS);
    float ux = nx * ninv, uy = ny * ninv, uz = nz * ninv;

    int kid[SL_HALF];
    const int4* kp = reinterpret_cast<const int4*>(knn + (size_t)p * SL_K + h * SL_HALF);
#pragma unroll
    for (int j = 0; j < 4; ++j) {
        int4 q = kp[j];
        kid[4 * j + 0] = q.x; kid[4 * j + 1] = q.y;
        kid[4 * j + 2] = q.z; kid[4 * j + 3] = q.w;
    }
    float numx = 0.f, numy = 0.f, numz = 0.f, den = 0.f;
#pragma unroll
    for (int k = 0; k < SL_HALF; ++k) {
        int idx = kid[k];
        int off = idx * 3;
        bool last = (idx == SL_P - 1);
        float4 v = *reinterpret_cast<const float4*>(nb + (last ? off - 1 : off));
        float kx = last ? v.y : v.x;
        float ky = last ? v.z : v.y;
        float kz = last ? v.w : v.z;
        float kinv = 1.0f / fmaxf(sqrtf(kx * kx + ky * ky + kz * kz), SL_EPS);
        float dx = fmaf(kx, kinv, -ux);
        float dy = fmaf(ky, kinv, -uy);
        float dz = fmaf(kz, kinv, -uz);
        float d2 = dx * dx + dy * dy + dz * dz;
        float w = __expf(-d2 * 1.77777779f);
        numx = fmaf(kx, w, numx);
        numy = fmaf(ky, w, numy);
        numz = fmaf(kz, w, numz);
        den += w;
    }
    numx += __shfl_xor(numx, 1);
    numy += __shfl_xor(numy, 1);
    numz += __shfl_xor(numz, 1);
    den  += __shfl_xor(den, 1);
    if (h == 0) {
        float dinv = 1.0f / fmaxf(den, SL_EPS);
        out[3 * (size_t)p + 0] = numx * dinv;
        out[3 * (size_t)p + 1] = numy * dinv;
        out[3 * (size_t)p + 2] = numz * dinv;
    }
}

extern "C" void kernel_launch(void* const* d_in, const int* in_sizes, int n_in,
                              void* d_out, int out_size, void* d_ws, size_t ws_size,
                              hipStream_t stream) {
    const float* normals = (const float*)d_in[0];
    const int*   knn     = (const int*)d_in[1];
    float*       out     = (float*)d_out;

    const size_t need = (size_t)SL_B * SL_P * sizeof(float2);  // 3.2 MB
    if (ws_size >= need) {
        float2* rec = (float2*)d_ws;
        int n1 = SL_B * SL_P;
        sl_pack<<<(n1 + 255) / 256, 256, 0, stream>>>(normals, rec);
        int n2 = SL_B * SL_P * 2;
        sl_main<<<(n2 + 255) / 256, 256, 0, stream>>>(rec, knn, out);
    } else {
        int n2 = SL_B * SL_P * 2;
        sl_fallback<<<(n2 + 255) / 256, 256, 0, stream>>>(normals, knn, out);
    }
}